// Round 17
// baseline (168.641 us; speedup 1.0000x reference)
//
#include <hip/hip_runtime.h>
#include <hip/hip_bf16.h>

#define TPB 256
#define CHUNK_LOG 13
#define CHUNK (1 << CHUNK_LOG)      // 8192 edges per histogram chunk
#define HSTRIDE 12544               // uints per chunk histogram (= 196*64, covers N<=50176)

typedef __attribute__((ext_vector_type(8))) short bf16x8;
typedef __attribute__((ext_vector_type(4))) float f32x4;
typedef __attribute__((ext_vector_type(2))) float f32x2;

__device__ inline unsigned short f2bf(float f) {
    unsigned u = __float_as_uint(f);
    unsigned r = u + 0x7fffu + ((u >> 16) & 1u);
    return (unsigned short)(r >> 16);
}
__device__ inline float bf2f(unsigned short s) {
    return __uint_as_float(((unsigned)s) << 16);
}

// ---- per-chunk LDS histogram (byte-packed) + per-edge local rank.
// Block 0 also zeroes the scan barrier counter (kernel boundary publishes it).
__global__ void k_hist(const int* __restrict__ dst,
                       unsigned* __restrict__ hist32, unsigned char* __restrict__ lrank,
                       unsigned* ctr, int E) {
    __shared__ unsigned lhist[HSTRIDE];
    int b = blockIdx.x;
    if (b == 0 && threadIdx.x == 0) *ctr = 0u;
    for (int i = threadIdx.x; i < HSTRIDE; i += TPB) lhist[i] = 0;
    __syncthreads();
    int e0 = b << CHUNK_LOG;
    int e1 = min(e0 + CHUNK, E);
    for (int e = e0 + (int)threadIdx.x; e < e1; e += TPB) {
        int d = dst[e];
        unsigned sh = (d & 3) * 8;
        unsigned old = atomicAdd(&lhist[d >> 2], 1u << sh);   // LDS atomic
        lrank[e] = (unsigned char)((old >> sh) & 0xffu);
    }
    __syncthreads();
    for (int i = threadIdx.x; i < HSTRIDE; i += TPB)
        hist32[(size_t)b * HSTRIDE + i] = lhist[i];
}

// ---- merged colscan + offs with narrow hand-rolled barrier (R11-proven):
// agent-scope atomics on NB ints, no L2 flush. 196 blocks co-resident. ----
__launch_bounds__(TPB)
__global__ void k_scan(const unsigned* __restrict__ hist32,
                       unsigned short* __restrict__ cbase,
                       int* __restrict__ bsum, unsigned* ctr,
                       int* __restrict__ offs, int N, int E, int NBH) {
    extern __shared__ unsigned tile[];          // NBH x 64 uints
    __shared__ int sdata[4];
    __shared__ int sb[TPB];
    __shared__ int wsum[4];
    int NB = gridDim.x;                         // must be <= TPB
    int bid = blockIdx.x, tid = threadIdx.x;
    int lane = tid & 63, w = tid >> 6;

    int tileBase = bid * 64;
    int total = NBH * 64;
    for (int i = tid; i < total; i += TPB) {
        int b = i >> 6, c = i & 63;
        tile[i] = hist32[(size_t)b * HSTRIDE + tileBase + c];
    }
    __syncthreads();
    int n = bid * TPB + tid;
    unsigned sh = (tid & 3) * 8;
    int wcol = tid >> 2;
    int run = 0;
    for (int b = 0; b < NBH; ++b) {
        int c = (int)((tile[b * 64 + wcol] >> sh) & 0xffu);
        if (n < N) cbase[(size_t)b * N + n] = (unsigned short)run;
        run += c;
    }
    int dv = (n < N) ? run : 0;                 // this node's degree (register)

    int s = dv;
    for (int o = 32; o; o >>= 1) s += __shfl_xor(s, o);
    if (lane == 0) sdata[w] = s;
    __syncthreads();
    if (tid == 0) {
        int tot = sdata[0] + sdata[1] + sdata[2] + sdata[3];
        __hip_atomic_store(&bsum[bid], tot, __ATOMIC_RELAXED, __HIP_MEMORY_SCOPE_AGENT);
        __hip_atomic_fetch_add(ctr, 1u, __ATOMIC_RELEASE, __HIP_MEMORY_SCOPE_AGENT);
        while (__hip_atomic_load(ctr, __ATOMIC_ACQUIRE, __HIP_MEMORY_SCOPE_AGENT)
               < (unsigned)NB)
            __builtin_amdgcn_s_sleep(2);
    }
    __syncthreads();

    int v = 0;
    if (tid < NB)
        v = __hip_atomic_load(&bsum[tid], __ATOMIC_RELAXED, __HIP_MEMORY_SCOPE_AGENT);
    int x = v;
    for (int o = 1; o < 64; o <<= 1) { int y = __shfl_up(x, o); if (lane >= o) x += y; }
    if (lane == 63) wsum[w] = x;
    __syncthreads();
    int add = 0;
    for (int k = 0; k < w; ++k) add += wsum[k];
    sb[tid] = add + x - v;                      // exclusive chunk prefix
    __syncthreads();
    int base = sb[bid];

    int y2 = dv;
    for (int o = 1; o < 64; o <<= 1) { int z = __shfl_up(y2, o); if (lane >= o) y2 += z; }
    __syncthreads();
    if (lane == 63) wsum[w] = y2;
    __syncthreads();
    int add2 = 0;
    for (int k = 0; k < w; ++k) add2 += wsum[k];
    int ex = base + add2 + y2 - dv;
    if (n < N) offs[n] = ex;
    if (n == N - 1) offs[N] = E;
}

// ---- fused: streaming convert (HBM-bound) + XCD-sliced scatter (L2-latency-
// bound). h8 now written SLICE-MAJOR: h8s[slice][n][16B] (slice = 16 fp8
// cols) so each XCD's gather working set in k_agg is 800KB -> L2-resident. ----
__global__ void k_scatterconv(const float* __restrict__ h, const float* __restrict__ W,
                              const int* __restrict__ src, const int* __restrict__ dst,
                              const unsigned char* __restrict__ lrank,
                              const unsigned short* __restrict__ cbase,
                              const int* __restrict__ offs,
                              unsigned short* __restrict__ esrc,
                              unsigned short* __restrict__ h_hi,
                              char* __restrict__ h8s,
                              unsigned short* __restrict__ Wb,
                              int N, int E, int nchunk) {
    // --- conv part (grid-stride over h + W float4 groups)
    int nh4 = N * 32;
    int totalc = nh4 + 8192;
    for (int t = blockIdx.x * TPB + threadIdx.x; t < totalc; t += gridDim.x * TPB) {
        if (t < nh4) {
            float4 v = ((const float4*)h)[t];
            ushort4 hi;
            hi.x = f2bf(v.x); hi.y = f2bf(v.y);
            hi.z = f2bf(v.z); hi.w = f2bf(v.w);
            ((ushort4*)h_hi)[t] = hi;
            int p8 = __builtin_amdgcn_cvt_pk_fp8_f32(v.x, v.y, 0, false);
            p8 = __builtin_amdgcn_cvt_pk_fp8_f32(v.z, v.w, p8, true);
            int row = t >> 5;
            int k4 = (t & 31) << 2;             // byte col 0..124
            int sl = k4 >> 4;                   // slice 0..7
            int ko = k4 & 15;
            *(unsigned*)(h8s + ((size_t)sl * N + row) * 16 + ko) = (unsigned)p8;
        } else {
            int w4 = t - nh4;
            float4 v = ((const float4*)W)[w4];
            ushort4 hi;
            hi.x = f2bf(v.x); hi.y = f2bf(v.y);
            hi.z = f2bf(v.z); hi.w = f2bf(v.w);
            ((ushort4*)Wb)[w4] = hi;
        }
    }
    // --- scatter part: slice = blockIdx&7 -> one XCD owns each esrc range
    int slice = blockIdx.x & 7;
    int chunk = blockIdx.x >> 3;
    int lo = (int)((long long)N * slice >> 3);
    int hi = (int)((long long)N * (slice + 1) >> 3);
    for (int e = chunk * TPB + threadIdx.x; e < E; e += nchunk * TPB) {
        int d = dst[e];
        if (d >= lo && d < hi) {
            int b = e >> CHUNK_LOG;
            int pos = offs[d] + (int)cbase[(size_t)b * N + d] + (int)lrank[e];
            esrc[pos] = (unsigned short)src[e];
        }
    }
}

// ---- XCD-column-sliced mean aggregate: block slice=blockIdx&7 lands on one
// XCD and gathers ONLY from its 800KB h8s slice -> L2-resident. One wave per
// node per slice: 16 edge-groups x 4 lanes x 4B = 16B slice-row per edge;
// uniform loop (no divergence); butterfly shfl_xor (cl-preserving) reduces
// the 16 edge-groups. c8s written in the same sliced layout (XCD-local). ----
__global__ void k_agg(const char* __restrict__ h8s, const int* __restrict__ offs,
                      const unsigned short* __restrict__ esrc,
                      char* __restrict__ c8s, int N) {
    int slice = blockIdx.x & 7;
    int wave = threadIdx.x >> 6;
    int lane = threadIdx.x & 63;
    int eg = lane >> 2, cl = lane & 3;
    int n = (blockIdx.x >> 3) * 4 + wave;
    if (n >= N) return;
    const char* hb = h8s + (size_t)slice * N * 16;
    int beg = offs[n], end = offs[n + 1];
    float a0 = 0.f, a1 = 0.f, a2 = 0.f, a3 = 0.f;
    for (int base = beg; base < end; base += 16) {
        int e = base + eg;
        unsigned u = 0;
        if (e < end) {
            int s = esrc[e];
            u = *(const unsigned*)(hb + (size_t)s * 16 + cl * 4);
        }
        f32x2 p = __builtin_amdgcn_cvt_pk_f32_fp8((int)u, false);
        f32x2 q = __builtin_amdgcn_cvt_pk_f32_fp8((int)u, true);
        a0 += p.x; a1 += p.y; a2 += q.x; a3 += q.y;
    }
    // butterfly over edge-group bits (lane bits 2..5); cl preserved
    for (int o = 4; o <= 32; o <<= 1) {
        a0 += __shfl_xor(a0, o);
        a1 += __shfl_xor(a1, o);
        a2 += __shfl_xor(a2, o);
        a3 += __shfl_xor(a3, o);
    }
    if (eg == 0) {
        float inv = 1.0f / fmaxf((float)(end - beg), 1.0f);
        int pk = __builtin_amdgcn_cvt_pk_fp8_f32(a0 * inv, a1 * inv, 0, false);
        pk = __builtin_amdgcn_cvt_pk_fp8_f32(a2 * inv, a3 * inv, pk, true);
        *(unsigned*)(c8s + ((size_t)slice * N + n) * 16 + cl * 4) = (unsigned)pk;
    }
}

// ---- MFMA NodeApply, 32 rows/wave, no LDS: A-frags from h_hi (k<128) and
// sliced fp8 c (k>=128; 8B uint2 never crosses a 16B slice chunk); residual
// from bf2f(h_hi); out stored nontemporal. ----
__launch_bounds__(TPB)
__global__ void k_apply(const unsigned short* __restrict__ h_hi,
                        const char* __restrict__ c8s,
                        const unsigned short* __restrict__ Wb,
                        const float* __restrict__ bia,
                        const float* __restrict__ snorm,
                        float* __restrict__ out, int N) {
    int lane = threadIdx.x & 63;
    int l15 = lane & 15, l4 = lane >> 4;
    int wave = threadIdx.x >> 6;
    int r0 = blockIdx.x * 128 + wave * 32;

    f32x4 acc[2][8] = {};

    #pragma unroll
    for (int kc = 0; kc < 8; ++kc) {
        bf16x8 Bf[8];
        #pragma unroll
        for (int n = 0; n < 8; ++n) {
            Bf[n] = *(const bf16x8*)((const char*)Wb +
                     ((size_t)(n * 16 + l15) * 512 + (size_t)kc * 64 + (size_t)l4 * 16));
        }
        #pragma unroll
        for (int rf = 0; rf < 2; ++rf) {
            int row = r0 + rf * 16 + l15;
            if (row > N - 1) row = N - 1;
            bf16x8 av;
            if (kc < 4) {
                av = *(const bf16x8*)((const char*)h_hi +
                      ((size_t)row * 256 + (size_t)kc * 64 + (size_t)l4 * 16));
            } else {
                int off = (kc - 4) * 32 + l4 * 8;    // byte col 0..120
                int sl = off >> 4;
                int ko = off & 15;                   // 0 or 8
                uint2 cu = *(const uint2*)(c8s + ((size_t)sl * N + row) * 16 + ko);
                f32x2 p = __builtin_amdgcn_cvt_pk_f32_fp8((int)cu.x, false);
                f32x2 q = __builtin_amdgcn_cvt_pk_f32_fp8((int)cu.x, true);
                f32x2 r = __builtin_amdgcn_cvt_pk_f32_fp8((int)cu.y, false);
                f32x2 s = __builtin_amdgcn_cvt_pk_f32_fp8((int)cu.y, true);
                union { unsigned u[4]; bf16x8 v; } cv;
                asm("v_cvt_pk_bf16_f32 %0, %1, %2" : "=v"(cv.u[0]) : "v"(p.x), "v"(p.y));
                asm("v_cvt_pk_bf16_f32 %0, %1, %2" : "=v"(cv.u[1]) : "v"(q.x), "v"(q.y));
                asm("v_cvt_pk_bf16_f32 %0, %1, %2" : "=v"(cv.u[2]) : "v"(r.x), "v"(r.y));
                asm("v_cvt_pk_bf16_f32 %0, %1, %2" : "=v"(cv.u[3]) : "v"(s.x), "v"(s.y));
                av = cv.v;
            }
            #pragma unroll
            for (int n = 0; n < 8; ++n)
                acc[rf][n] = __builtin_amdgcn_mfma_f32_16x16x32_bf16(av, Bf[n], acc[rf][n], 0, 0, 0);
        }
    }

    float bn[8];
    #pragma unroll
    for (int n = 0; n < 8; ++n) bn[n] = bia[n * 16 + l15];

    #pragma unroll
    for (int rf = 0; rf < 2; ++rf) {
        float sq[4] = {0.f, 0.f, 0.f, 0.f};
        #pragma unroll
        for (int n = 0; n < 8; ++n) {
            #pragma unroll
            for (int g = 0; g < 4; ++g) {
                acc[rf][n][g] += bn[n];
                sq[g] += acc[rf][n][g] * acc[rf][n][g];
            }
        }
        #pragma unroll
        for (int g = 0; g < 4; ++g) {
            sq[g] += __shfl_xor(sq[g], 1);
            sq[g] += __shfl_xor(sq[g], 2);
            sq[g] += __shfl_xor(sq[g], 4);
            sq[g] += __shfl_xor(sq[g], 8);
        }
        #pragma unroll
        for (int g = 0; g < 4; ++g) {
            int row = r0 + rf * 16 + l4 * 4 + g;
            if (row < N) {
                float invn = 1.0f / fmaxf(sqrtf(sq[g]), 1e-12f);
                float sn = snorm[row];
                #pragma unroll
                for (int n = 0; n < 8; ++n) {
                    int col = n * 16 + l15;
                    float res = bf2f(h_hi[(size_t)row * 128 + col]);
                    float v = fmaxf(acc[rf][n][g] * invn, 0.f) * sn + res;
                    __builtin_nontemporal_store(v, &out[(size_t)row * 128 + col]);
                }
            }
        }
    }
}

extern "C" void kernel_launch(void* const* d_in, const int* in_sizes, int n_in,
                              void* d_out, int out_size, void* d_ws, size_t ws_size,
                              hipStream_t stream) {
    const float* h     = (const float*)d_in[0];
    const float* snorm = (const float*)d_in[1];
    const float* W     = (const float*)d_in[2];
    const float* b     = (const float*)d_in[3];
    const int*   src   = (const int*)d_in[4];
    const int*   dst   = (const int*)d_in[5];
    int N = in_sizes[1];
    int E = in_sizes[4];
    float* out = (float*)d_out;

    char* ws = (char*)d_ws;
    size_t off = 0;
    auto alloc = [&](size_t bytes) {
        void* ptr = ws + off;
        off = (off + bytes + 255) & ~(size_t)255;
        return ptr;
    };
    int NB  = (N + TPB - 1) / TPB;              // 196 (<= TPB required by k_scan)
    int NBH = (E + CHUNK - 1) >> CHUNK_LOG;     // 98 chunks of 8192 edges
    int* offs   = (int*)alloc((size_t)(N + 1) * 4);
    int* bsum   = (int*)alloc((size_t)NB * 4);
    unsigned* ctr          = (unsigned*)alloc(256);
    unsigned* hist32       = (unsigned*)alloc((size_t)NBH * HSTRIDE * 4);
    unsigned short* cbase  = (unsigned short*)alloc((size_t)NBH * N * 2);
    unsigned char*  lrank  = (unsigned char*)alloc((size_t)E);
    unsigned short* esrc   = (unsigned short*)alloc((size_t)E * 2);
    unsigned short* h_hi   = (unsigned short*)alloc((size_t)N * 128 * 2);
    char*           h8s    = (char*)alloc((size_t)N * 128);
    unsigned short* Wb     = (unsigned short*)alloc((size_t)128 * 256 * 2);
    // c8s[8][N][16B] (6.4MB) aliases hist32+cbase (4.9+9.8=14.7MB >= 6.4MB):
    // hist32 dead after k_scan, cbase after k_scatterconv; k_agg (first writer
    // of c8s) runs after both.
    char* c8s = (char*)hist32;

    k_hist<<<NBH, TPB, 0, stream>>>(dst, hist32, lrank, ctr, E);

    size_t tile_bytes = (size_t)NBH * 64 * 4;
    k_scan<<<NB, TPB, tile_bytes, stream>>>(hist32, cbase, bsum, ctr, offs, N, E, NBH);

    int nchunk = 512;
    k_scatterconv<<<8 * nchunk, TPB, 0, stream>>>(h, W, src, dst, lrank, cbase, offs,
                                                  esrc, h_hi, h8s, Wb, N, E, nchunk);

    int aggblk = 8 * ((N + 3) / 4);             // 8 slices x 4-node chunks
    k_agg<<<aggblk, TPB, 0, stream>>>(h8s, offs, esrc, c8s, N);

    int nblk = (N + 127) / 128;
    k_apply<<<nblk, TPB, 0, stream>>>(h_hi, c8s, Wb, b, snorm, out, N);
}

// Round 18
// 102.405 us; speedup vs baseline: 1.6468x; 1.6468x over previous
//
#include <hip/hip_runtime.h>
#include <hip/hip_bf16.h>

#define TPB 256
#define CHUNK_LOG 13
#define CHUNK (1 << CHUNK_LOG)      // 8192 edges per histogram chunk
#define HSTRIDE 12544               // uints per chunk histogram (= 196*64, covers N<=50176)

typedef __attribute__((ext_vector_type(8))) short bf16x8;
typedef __attribute__((ext_vector_type(4))) float f32x4;
typedef __attribute__((ext_vector_type(2))) float f32x2;

__device__ inline unsigned short f2bf(float f) {
    unsigned u = __float_as_uint(f);
    unsigned r = u + 0x7fffu + ((u >> 16) & 1u);
    return (unsigned short)(r >> 16);
}
__device__ inline float bf2f(unsigned short s) {
    return __uint_as_float(((unsigned)s) << 16);
}

// ---- per-chunk LDS histogram (byte-packed) + per-edge local rank.
// Block 0 also zeroes the scan barrier counter (kernel boundary publishes it).
__global__ void k_hist(const int* __restrict__ dst,
                       unsigned* __restrict__ hist32, unsigned char* __restrict__ lrank,
                       unsigned* ctr, int E) {
    __shared__ unsigned lhist[HSTRIDE];
    int b = blockIdx.x;
    if (b == 0 && threadIdx.x == 0) *ctr = 0u;
    for (int i = threadIdx.x; i < HSTRIDE; i += TPB) lhist[i] = 0;
    __syncthreads();
    int e0 = b << CHUNK_LOG;
    int e1 = min(e0 + CHUNK, E);
    for (int e = e0 + (int)threadIdx.x; e < e1; e += TPB) {
        int d = dst[e];
        unsigned sh = (d & 3) * 8;
        unsigned old = atomicAdd(&lhist[d >> 2], 1u << sh);   // LDS atomic
        lrank[e] = (unsigned char)((old >> sh) & 0xffu);
    }
    __syncthreads();
    for (int i = threadIdx.x; i < HSTRIDE; i += TPB)
        hist32[(size_t)b * HSTRIDE + i] = lhist[i];
}

// ---- merged colscan + offs with narrow hand-rolled barrier (R11-proven):
// agent-scope atomics on NB ints, no L2 flush. 196 blocks co-resident. ----
__launch_bounds__(TPB)
__global__ void k_scan(const unsigned* __restrict__ hist32,
                       unsigned short* __restrict__ cbase,
                       int* __restrict__ bsum, unsigned* ctr,
                       int* __restrict__ offs, int N, int E, int NBH) {
    extern __shared__ unsigned tile[];          // NBH x 64 uints
    __shared__ int sdata[4];
    __shared__ int sb[TPB];
    __shared__ int wsum[4];
    int NB = gridDim.x;                         // must be <= TPB
    int bid = blockIdx.x, tid = threadIdx.x;
    int lane = tid & 63, w = tid >> 6;

    int tileBase = bid * 64;
    int total = NBH * 64;
    for (int i = tid; i < total; i += TPB) {
        int b = i >> 6, c = i & 63;
        tile[i] = hist32[(size_t)b * HSTRIDE + tileBase + c];
    }
    __syncthreads();
    int n = bid * TPB + tid;
    unsigned sh = (tid & 3) * 8;
    int wcol = tid >> 2;
    int run = 0;
    for (int b = 0; b < NBH; ++b) {
        int c = (int)((tile[b * 64 + wcol] >> sh) & 0xffu);
        if (n < N) cbase[(size_t)b * N + n] = (unsigned short)run;
        run += c;
    }
    int dv = (n < N) ? run : 0;                 // this node's degree (register)

    int s = dv;
    for (int o = 32; o; o >>= 1) s += __shfl_xor(s, o);
    if (lane == 0) sdata[w] = s;
    __syncthreads();
    if (tid == 0) {
        int tot = sdata[0] + sdata[1] + sdata[2] + sdata[3];
        __hip_atomic_store(&bsum[bid], tot, __ATOMIC_RELAXED, __HIP_MEMORY_SCOPE_AGENT);
        __hip_atomic_fetch_add(ctr, 1u, __ATOMIC_RELEASE, __HIP_MEMORY_SCOPE_AGENT);
        while (__hip_atomic_load(ctr, __ATOMIC_ACQUIRE, __HIP_MEMORY_SCOPE_AGENT)
               < (unsigned)NB)
            __builtin_amdgcn_s_sleep(2);
    }
    __syncthreads();

    int v = 0;
    if (tid < NB)
        v = __hip_atomic_load(&bsum[tid], __ATOMIC_RELAXED, __HIP_MEMORY_SCOPE_AGENT);
    int x = v;
    for (int o = 1; o < 64; o <<= 1) { int y = __shfl_up(x, o); if (lane >= o) x += y; }
    if (lane == 63) wsum[w] = x;
    __syncthreads();
    int add = 0;
    for (int k = 0; k < w; ++k) add += wsum[k];
    sb[tid] = add + x - v;                      // exclusive chunk prefix
    __syncthreads();
    int base = sb[bid];

    int y2 = dv;
    for (int o = 1; o < 64; o <<= 1) { int z = __shfl_up(y2, o); if (lane >= o) y2 += z; }
    __syncthreads();
    if (lane == 63) wsum[w] = y2;
    __syncthreads();
    int add2 = 0;
    for (int k = 0; k < w; ++k) add2 += wsum[k];
    int ex = base + add2 + y2 - dv;
    if (n < N) offs[n] = ex;
    if (n == N - 1) offs[N] = E;
}

// ---- fused: streaming convert (HBM-bound) + XCD-sliced scatter (L2-latency-
// bound) — phases overlap across blocks, one dispatch boundary removed. ----
__global__ void k_scatterconv(const float* __restrict__ h, const float* __restrict__ W,
                              const int* __restrict__ src, const int* __restrict__ dst,
                              const unsigned char* __restrict__ lrank,
                              const unsigned short* __restrict__ cbase,
                              const int* __restrict__ offs,
                              unsigned short* __restrict__ esrc,
                              unsigned short* __restrict__ h_hi,
                              unsigned* __restrict__ h8,
                              unsigned short* __restrict__ Wb,
                              int N, int E, int nchunk) {
    // --- conv part (grid-stride over h + W float4 groups)
    int nh4 = N * 32;
    int totalc = nh4 + 8192;
    for (int t = blockIdx.x * TPB + threadIdx.x; t < totalc; t += gridDim.x * TPB) {
        if (t < nh4) {
            float4 v = ((const float4*)h)[t];
            ushort4 hi;
            hi.x = f2bf(v.x); hi.y = f2bf(v.y);
            hi.z = f2bf(v.z); hi.w = f2bf(v.w);
            ((ushort4*)h_hi)[t] = hi;
            int p8 = __builtin_amdgcn_cvt_pk_fp8_f32(v.x, v.y, 0, false);
            p8 = __builtin_amdgcn_cvt_pk_fp8_f32(v.z, v.w, p8, true);
            h8[t] = (unsigned)p8;               // 4 fp8 per uint, [x,y,z,w]
        } else {
            int w4 = t - nh4;
            float4 v = ((const float4*)W)[w4];
            ushort4 hi;
            hi.x = f2bf(v.x); hi.y = f2bf(v.y);
            hi.z = f2bf(v.z); hi.w = f2bf(v.w);
            ((ushort4*)Wb)[w4] = hi;
        }
    }
    // --- scatter part: slice = blockIdx&7 -> one XCD owns each esrc range
    int slice = blockIdx.x & 7;
    int chunk = blockIdx.x >> 3;
    int lo = (int)((long long)N * slice >> 3);
    int hi = (int)((long long)N * (slice + 1) >> 3);
    for (int e = chunk * TPB + threadIdx.x; e < E; e += nchunk * TPB) {
        int d = dst[e];
        if (d >= lo && d < hi) {
            int b = e >> CHUNK_LOG;
            int pos = offs[d] + (int)cbase[(size_t)b * N + d] + (int)lrank[e];
            esrc[pos] = (unsigned short)src[e];
        }
    }
}

#define AGG_ACC(u)                                                            \
    {                                                                         \
        f32x2 _p = __builtin_amdgcn_cvt_pk_f32_fp8((int)(u), false);          \
        f32x2 _q = __builtin_amdgcn_cvt_pk_f32_fp8((int)(u), true);           \
        a0 += _p.x; a1 += _p.y; a2 += _q.x; a3 += _q.y;                       \
    }

// ---- mean aggregate over fp8 h8: two nodes per wave (half-wave each,
// 4B/lane covers the 128B row). 8-edge batches with a 2-stage SW pipeline:
// next batch's esrc indices prefetched while the current batch gathers,
// hiding the esrc->gather dependency latency. Output c packed fp8 (row=128B).
__global__ void k_agg(const unsigned* __restrict__ h8, const int* __restrict__ offs,
                      const unsigned short* __restrict__ esrc,
                      unsigned* __restrict__ c8, int N) {
    int wav = (blockIdx.x * TPB + threadIdx.x) >> 6;
    int half = (threadIdx.x >> 5) & 1;
    int hl = threadIdx.x & 31;
    int n = wav * 2 + half;
    if (n >= N) return;
    int beg = offs[n], end = offs[n + 1];
    int cnt = end - beg;
    float a0 = 0.f, a1 = 0.f, a2 = 0.f, a3 = 0.f;
    int e = beg;
    int s0 = 0, s1 = 0, s2 = 0, s3 = 0, s4 = 0, s5 = 0, s6 = 0, s7 = 0;
    if (cnt >= 8) {
        s0 = esrc[e];     s1 = esrc[e + 1]; s2 = esrc[e + 2]; s3 = esrc[e + 3];
        s4 = esrc[e + 4]; s5 = esrc[e + 5]; s6 = esrc[e + 6]; s7 = esrc[e + 7];
    }
    while (cnt >= 16) {
        // prefetch next batch's indices (independent of current gathers)
        int t0 = esrc[e + 8],  t1 = esrc[e + 9],  t2 = esrc[e + 10], t3 = esrc[e + 11];
        int t4 = esrc[e + 12], t5 = esrc[e + 13], t6 = esrc[e + 14], t7 = esrc[e + 15];
        unsigned u0 = h8[(size_t)s0 * 32 + hl];
        unsigned u1 = h8[(size_t)s1 * 32 + hl];
        unsigned u2 = h8[(size_t)s2 * 32 + hl];
        unsigned u3 = h8[(size_t)s3 * 32 + hl];
        unsigned u4 = h8[(size_t)s4 * 32 + hl];
        unsigned u5 = h8[(size_t)s5 * 32 + hl];
        unsigned u6 = h8[(size_t)s6 * 32 + hl];
        unsigned u7 = h8[(size_t)s7 * 32 + hl];
        AGG_ACC(u0) AGG_ACC(u1) AGG_ACC(u2) AGG_ACC(u3)
        AGG_ACC(u4) AGG_ACC(u5) AGG_ACC(u6) AGG_ACC(u7)
        s0 = t0; s1 = t1; s2 = t2; s3 = t3;
        s4 = t4; s5 = t5; s6 = t6; s7 = t7;
        e += 8; cnt -= 8;
    }
    if (cnt >= 8) {
        unsigned u0 = h8[(size_t)s0 * 32 + hl];
        unsigned u1 = h8[(size_t)s1 * 32 + hl];
        unsigned u2 = h8[(size_t)s2 * 32 + hl];
        unsigned u3 = h8[(size_t)s3 * 32 + hl];
        unsigned u4 = h8[(size_t)s4 * 32 + hl];
        unsigned u5 = h8[(size_t)s5 * 32 + hl];
        unsigned u6 = h8[(size_t)s6 * 32 + hl];
        unsigned u7 = h8[(size_t)s7 * 32 + hl];
        AGG_ACC(u0) AGG_ACC(u1) AGG_ACC(u2) AGG_ACC(u3)
        AGG_ACC(u4) AGG_ACC(u5) AGG_ACC(u6) AGG_ACC(u7)
        e += 8; cnt -= 8;
    }
    for (; cnt > 0; --cnt, ++e) {
        unsigned u0 = h8[(size_t)esrc[e] * 32 + hl];
        AGG_ACC(u0)
    }
    float inv = 1.0f / fmaxf((float)(end - beg), 1.0f);
    int pk = __builtin_amdgcn_cvt_pk_fp8_f32(a0 * inv, a1 * inv, 0, false);
    pk = __builtin_amdgcn_cvt_pk_fp8_f32(a2 * inv, a3 * inv, pk, true);
    c8[(size_t)n * 32 + hl] = (unsigned)pk;     // same byte layout as h8 rows
}

// ---- MFMA NodeApply, 32 rows/wave, no LDS: A-frags from h_hi (k<128) and
// fp8 c (k>=128, unpacked via cvt_pk_f32_fp8 + v_cvt_pk_bf16_f32); residual
// from bf2f(h_hi); out stored nontemporal. ----
__launch_bounds__(TPB)
__global__ void k_apply(const unsigned short* __restrict__ h_hi,
                        const unsigned char* __restrict__ c8,
                        const unsigned short* __restrict__ Wb,
                        const float* __restrict__ bia,
                        const float* __restrict__ snorm,
                        float* __restrict__ out, int N) {
    int lane = threadIdx.x & 63;
    int l15 = lane & 15, l4 = lane >> 4;
    int wave = threadIdx.x >> 6;
    int r0 = blockIdx.x * 128 + wave * 32;

    f32x4 acc[2][8] = {};

    #pragma unroll
    for (int kc = 0; kc < 8; ++kc) {
        bf16x8 Bf[8];
        #pragma unroll
        for (int n = 0; n < 8; ++n) {
            Bf[n] = *(const bf16x8*)((const char*)Wb +
                     ((size_t)(n * 16 + l15) * 512 + (size_t)kc * 64 + (size_t)l4 * 16));
        }
        #pragma unroll
        for (int rf = 0; rf < 2; ++rf) {
            int row = r0 + rf * 16 + l15;
            if (row > N - 1) row = N - 1;
            bf16x8 av;
            if (kc < 4) {
                av = *(const bf16x8*)((const char*)h_hi +
                      ((size_t)row * 256 + (size_t)kc * 64 + (size_t)l4 * 16));
            } else {
                uint2 cu = *(const uint2*)(c8 + (size_t)row * 128 +
                            (size_t)(kc - 4) * 32 + (size_t)l4 * 8);
                f32x2 p = __builtin_amdgcn_cvt_pk_f32_fp8((int)cu.x, false);
                f32x2 q = __builtin_amdgcn_cvt_pk_f32_fp8((int)cu.x, true);
                f32x2 r = __builtin_amdgcn_cvt_pk_f32_fp8((int)cu.y, false);
                f32x2 s = __builtin_amdgcn_cvt_pk_f32_fp8((int)cu.y, true);
                union { unsigned u[4]; bf16x8 v; } cv;
                asm("v_cvt_pk_bf16_f32 %0, %1, %2" : "=v"(cv.u[0]) : "v"(p.x), "v"(p.y));
                asm("v_cvt_pk_bf16_f32 %0, %1, %2" : "=v"(cv.u[1]) : "v"(q.x), "v"(q.y));
                asm("v_cvt_pk_bf16_f32 %0, %1, %2" : "=v"(cv.u[2]) : "v"(r.x), "v"(r.y));
                asm("v_cvt_pk_bf16_f32 %0, %1, %2" : "=v"(cv.u[3]) : "v"(s.x), "v"(s.y));
                av = cv.v;
            }
            #pragma unroll
            for (int n = 0; n < 8; ++n)
                acc[rf][n] = __builtin_amdgcn_mfma_f32_16x16x32_bf16(av, Bf[n], acc[rf][n], 0, 0, 0);
        }
    }

    float bn[8];
    #pragma unroll
    for (int n = 0; n < 8; ++n) bn[n] = bia[n * 16 + l15];

    #pragma unroll
    for (int rf = 0; rf < 2; ++rf) {
        float sq[4] = {0.f, 0.f, 0.f, 0.f};
        #pragma unroll
        for (int n = 0; n < 8; ++n) {
            #pragma unroll
            for (int g = 0; g < 4; ++g) {
                acc[rf][n][g] += bn[n];
                sq[g] += acc[rf][n][g] * acc[rf][n][g];
            }
        }
        #pragma unroll
        for (int g = 0; g < 4; ++g) {
            sq[g] += __shfl_xor(sq[g], 1);
            sq[g] += __shfl_xor(sq[g], 2);
            sq[g] += __shfl_xor(sq[g], 4);
            sq[g] += __shfl_xor(sq[g], 8);
        }
        #pragma unroll
        for (int g = 0; g < 4; ++g) {
            int row = r0 + rf * 16 + l4 * 4 + g;
            if (row < N) {
                float invn = 1.0f / fmaxf(sqrtf(sq[g]), 1e-12f);
                float sn = snorm[row];
                #pragma unroll
                for (int n = 0; n < 8; ++n) {
                    int col = n * 16 + l15;
                    float res = bf2f(h_hi[(size_t)row * 128 + col]);
                    float v = fmaxf(acc[rf][n][g] * invn, 0.f) * sn + res;
                    __builtin_nontemporal_store(v, &out[(size_t)row * 128 + col]);
                }
            }
        }
    }
}

extern "C" void kernel_launch(void* const* d_in, const int* in_sizes, int n_in,
                              void* d_out, int out_size, void* d_ws, size_t ws_size,
                              hipStream_t stream) {
    const float* h     = (const float*)d_in[0];
    const float* snorm = (const float*)d_in[1];
    const float* W     = (const float*)d_in[2];
    const float* b     = (const float*)d_in[3];
    const int*   src   = (const int*)d_in[4];
    const int*   dst   = (const int*)d_in[5];
    int N = in_sizes[1];
    int E = in_sizes[4];
    float* out = (float*)d_out;

    char* ws = (char*)d_ws;
    size_t off = 0;
    auto alloc = [&](size_t bytes) {
        void* ptr = ws + off;
        off = (off + bytes + 255) & ~(size_t)255;
        return ptr;
    };
    int NB  = (N + TPB - 1) / TPB;              // 196 (<= TPB required by k_scan)
    int NBH = (E + CHUNK - 1) >> CHUNK_LOG;     // 98 chunks of 8192 edges
    int* offs   = (int*)alloc((size_t)(N + 1) * 4);
    int* bsum   = (int*)alloc((size_t)NB * 4);
    unsigned* ctr          = (unsigned*)alloc(256);
    unsigned* hist32       = (unsigned*)alloc((size_t)NBH * HSTRIDE * 4);
    unsigned short* cbase  = (unsigned short*)alloc((size_t)NBH * N * 2);
    unsigned char*  lrank  = (unsigned char*)alloc((size_t)E);
    unsigned short* esrc   = (unsigned short*)alloc((size_t)E * 2);
    unsigned short* h_hi   = (unsigned short*)alloc((size_t)N * 128 * 2);
    unsigned*       h8     = (unsigned*)alloc((size_t)N * 128);
    unsigned short* Wb     = (unsigned short*)alloc((size_t)128 * 256 * 2);
    // c8[N][128B fp8] (6.4MB) aliases hist32+cbase (4.9+9.8=14.7MB >= 6.4MB):
    // hist32 dead after k_scan, cbase after k_scatterconv; k_agg (first writer
    // of c8) runs after both.
    unsigned* c8 = hist32;

    k_hist<<<NBH, TPB, 0, stream>>>(dst, hist32, lrank, ctr, E);

    size_t tile_bytes = (size_t)NBH * 64 * 4;
    k_scan<<<NB, TPB, tile_bytes, stream>>>(hist32, cbase, bsum, ctr, offs, N, E, NBH);

    int nchunk = 512;
    k_scatterconv<<<8 * nchunk, TPB, 0, stream>>>(h, W, src, dst, lrank, cbase, offs,
                                                  esrc, h_hi, h8, Wb, N, E, nchunk);

    int aggblk = (N + 7) / 8;                   // 8 nodes per block (2 per wave)
    k_agg<<<aggblk, TPB, 0, stream>>>(h8, offs, esrc, c8, N);

    int nblk = (N + 127) / 128;
    k_apply<<<nblk, TPB, 0, stream>>>(h_hi, (const unsigned char*)c8, Wb, b, snorm, out, N);
}